// Round 3
// baseline (455.298 us; speedup 1.0000x reference)
//
#include <hip/hip_runtime.h>
#include <math.h>

// EdgeEmbedding, split-phase. Theory (R2, untested — R1 infra fail, R2 compile fail):
// measured dur includes the harness's 1.6 GB poison fill (~260 us); the previous
// single-pass kernel was ~136 us = 3 TB/s effective, 2x over the 6.2 TB/s write ceiling
// fillBufferAligned demonstrates on this same buffer, because 99.2% of threads ran a
// full compute program just to store zeros.
// Phase 1: pure streaming zero of the 402.65 MB output (fillBuffer clone, ~65 us).
// Phase 2: sparse edge kernel — compute each pair's distance ONCE, early-out non-edges,
//          ~34k edge threads write 96 B each (~10 us). Same basis math as the passing
//          kernel (sinf seeds every 4 + 2cos recurrence) so absmax is unchanged.
// R2 fix: __builtin_nontemporal_store needs a clang ext_vector_type, not HIP float4.

#define NATOMS 2048
#define NBASIS 20
#define RCUT   5.0f

#define DIR_OFF   ((long long)NATOMS * NATOMS * NBASIS)        // floats
#define MASK_OFF  ((long long)NATOMS * NATOMS * (NBASIS + 3))  // floats

typedef float f32x4 __attribute__((ext_vector_type(4)));

#define ZBLOCKS  4096
#define ZTHREADS 256
#define ZITERS   24   // 4096*256*24 == 25,165,824 float4 == 402.65 MB exactly

__global__ __launch_bounds__(ZTHREADS) void edge_zero_kernel(f32x4* __restrict__ out)
{
    const long long tid    = (long long)blockIdx.x * blockDim.x + threadIdx.x;
    const long long stride = (long long)gridDim.x * blockDim.x;
    const f32x4 z = (f32x4)(0.0f);
#pragma unroll
    for (int k = 0; k < ZITERS; ++k) {
        // each iteration the whole grid writes one contiguous 16 MB slab; per-wave
        // 1024 B contiguous per instruction, 24 stores in flight per wave
        __builtin_nontemporal_store(z, out + tid + (long long)k * stride);
    }
}

#define EBLOCK 256   // 8 blocks per row -> i is blockIdx-uniform (scalar pos[i] loads)

__global__ __launch_bounds__(EBLOCK) void edge_sparse_kernel(
    const float* __restrict__ pos, float* __restrict__ out)
{
    const int i = blockIdx.x >> 3;                         // 2048 rows
    const int j = ((blockIdx.x & 7) << 8) | threadIdx.x;   // 8*256 = 2048 cols

    const float xi = pos[3 * i + 0], yi = pos[3 * i + 1], zi = pos[3 * i + 2];
    const float xj = pos[3 * j + 0], yj = pos[3 * j + 1], zj = pos[3 * j + 2];
    const float dx = xi - xj, dy = yi - yj, dz = zi - zj;
    float d2;
    {
        // match numpy's unfused rounding so the dist<r mask can't flip at the boundary
#pragma clang fp contract(off)
        d2 = (dx * dx + dy * dy) + dz * dz;
    }
    const float dist = sqrtf(d2);
    if (!((dist < RCUT) && (i != j))) return;   // 99.2% of lanes exit here

    const float x  = dist * (1.0f / RCUT);
    const float x2 = x * x, x4 = x2 * x2, x8 = x4 * x4, x9 = x8 * x;
    const float env   = 1.0f - 55.0f * x9 + 99.0f * x9 * x - 45.0f * x9 * x2;
    const float scale = env / x;
    const float theta = 3.14159265358979323846f * x;
    const float twoc  = 2.0f * cosf(theta);

    const long long pair = (long long)i * NATOMS + j;
    float4* __restrict__ de = (float4*)out;
#pragma unroll
    for (int g = 0; g < 5; ++g) {
        // identical numeric structure to the verified kernel: two sinf seeds per
        // group of 4, two Chebyshev recurrence steps
        const float k0 = (float)(4 * g + 1);
        const float s0 = sinf(k0 * theta);
        const float s1 = sinf((k0 + 1.0f) * theta);
        const float s2 = twoc * s1 - s0;
        const float s3 = twoc * s2 - s1;
        de[pair * 5 + g] = make_float4(scale * s0, scale * s1, scale * s2, scale * s3);
    }

    const float inv = 1.0f / dist;
    float* __restrict__ dir = out + DIR_OFF + pair * 3;
    dir[0] = dx * inv; dir[1] = dy * inv; dir[2] = dz * inv;
    out[MASK_OFF + pair] = 1.0f;
}

extern "C" void kernel_launch(void* const* d_in, const int* in_sizes, int n_in,
                              void* d_out, int out_size, void* d_ws, size_t ws_size,
                              hipStream_t stream) {
    const float* pos = (const float*)d_in[0];
    // Phase 1: stream zeros over the whole 402.65 MB output at fill rate.
    edge_zero_kernel<<<dim3(ZBLOCKS), dim3(ZTHREADS), 0, stream>>>((f32x4*)d_out);
    // Phase 2: sparse edges only (same stream -> ordered after the zero pass).
    edge_sparse_kernel<<<dim3(NATOMS * (NATOMS / EBLOCK)), dim3(EBLOCK), 0, stream>>>(
        pos, (float*)d_out);
}

// Round 4
// 432.186 us; speedup vs baseline: 1.0535x; 1.0535x over previous
//
#include <hip/hip_runtime.h>
#include <math.h>

// EdgeEmbedding, split-phase, R4. R3 post-mortem: split with NONTEMPORAL zero stores
// regressed (396 -> 455; ours ~187 us vs 136 single-pass). Prime suspect: nt bit
// bypasses the L2 write-coalescing path plain stores use — fillBufferAligned hits
// 6 TB/s on this same buffer with PLAIN stores. Single-variable change: drop nt.
// Phase 1: plain-store streaming zero of the 402.65 MB output (fill clone, ~65 us).
// Phase 2: sparse edge kernel — distance once per pair, early-out 99.2% of lanes,
//          ~34k edge threads write 96 B each (~10 us). Basis math identical to the
//          verified kernel (sinf seeds every 4 + 2cos recurrence) so absmax holds.

#define NATOMS 2048
#define NBASIS 20
#define RCUT   5.0f

#define DIR_OFF   ((long long)NATOMS * NATOMS * NBASIS)        // floats
#define MASK_OFF  ((long long)NATOMS * NATOMS * (NBASIS + 3))  // floats

#define ZBLOCKS  4096
#define ZTHREADS 256
#define ZITERS   24   // 4096*256*24 == 25,165,824 float4 == 402.65 MB exactly

__global__ __launch_bounds__(ZTHREADS) void edge_zero_kernel(float4* __restrict__ out)
{
    const long long tid    = (long long)blockIdx.x * ZTHREADS + threadIdx.x;
    const long long stride = (long long)ZBLOCKS * ZTHREADS;
    const float4 z = make_float4(0.0f, 0.0f, 0.0f, 0.0f);
#pragma unroll
    for (int k = 0; k < ZITERS; ++k) {
        // plain stores, exactly like fillBufferAligned: each instruction is a
        // contiguous 1 KB per wave; 24 stores in flight per thread
        out[tid + (long long)k * stride] = z;
    }
}

#define EBLOCK 256   // 8 blocks per row -> i is blockIdx-uniform (scalar pos[i] loads)

__global__ __launch_bounds__(EBLOCK) void edge_sparse_kernel(
    const float* __restrict__ pos, float* __restrict__ out)
{
    const int i = blockIdx.x >> 3;                         // 2048 rows
    const int j = ((blockIdx.x & 7) << 8) | threadIdx.x;   // 8*256 = 2048 cols

    const float xi = pos[3 * i + 0], yi = pos[3 * i + 1], zi = pos[3 * i + 2];
    const float xj = pos[3 * j + 0], yj = pos[3 * j + 1], zj = pos[3 * j + 2];
    const float dx = xi - xj, dy = yi - yj, dz = zi - zj;
    float d2;
    {
        // match numpy's unfused rounding so the dist<r mask can't flip at the boundary
#pragma clang fp contract(off)
        d2 = (dx * dx + dy * dy) + dz * dz;
    }
    const float dist = sqrtf(d2);
    if (!((dist < RCUT) && (i != j))) return;   // 99.2% of lanes exit here

    const float x  = dist * (1.0f / RCUT);
    const float x2 = x * x, x4 = x2 * x2, x8 = x4 * x4, x9 = x8 * x;
    const float env   = 1.0f - 55.0f * x9 + 99.0f * x9 * x - 45.0f * x9 * x2;
    const float scale = env / x;
    const float theta = 3.14159265358979323846f * x;
    const float twoc  = 2.0f * cosf(theta);

    const long long pair = (long long)i * NATOMS + j;
    float4* __restrict__ de = (float4*)out;
#pragma unroll
    for (int g = 0; g < 5; ++g) {
        // identical numeric structure to the verified kernel: two sinf seeds per
        // group of 4, two Chebyshev recurrence steps
        const float k0 = (float)(4 * g + 1);
        const float s0 = sinf(k0 * theta);
        const float s1 = sinf((k0 + 1.0f) * theta);
        const float s2 = twoc * s1 - s0;
        const float s3 = twoc * s2 - s1;
        de[pair * 5 + g] = make_float4(scale * s0, scale * s1, scale * s2, scale * s3);
    }

    const float inv = 1.0f / dist;
    float* __restrict__ dir = out + DIR_OFF + pair * 3;
    dir[0] = dx * inv; dir[1] = dy * inv; dir[2] = dz * inv;
    out[MASK_OFF + pair] = 1.0f;
}

extern "C" void kernel_launch(void* const* d_in, const int* in_sizes, int n_in,
                              void* d_out, int out_size, void* d_ws, size_t ws_size,
                              hipStream_t stream) {
    const float* pos = (const float*)d_in[0];
    // Phase 1: stream zeros over the whole 402.65 MB output at fill rate.
    edge_zero_kernel<<<dim3(ZBLOCKS), dim3(ZTHREADS), 0, stream>>>((float4*)d_out);
    // Phase 2: sparse edges only (same stream -> ordered after the zero pass).
    edge_sparse_kernel<<<dim3(NATOMS * (NATOMS / EBLOCK)), dim3(EBLOCK), 0, stream>>>(
        pos, (float*)d_out);
}

// Round 6
// 400.561 us; speedup vs baseline: 1.1367x; 1.0790x over previous
//
#include <hip/hip_runtime.h>
#include <math.h>

// EdgeEmbedding single-pass, R6 (= R5 + missing `out` decl fix). R4 post-mortem: the
// split (zero+sparse) ran at the same ~3 TB/s effective as R0's single-pass but added
// overhead -> reverted to the verified R0 structure (5 threads/pair, contiguous
// 16B/lane de stores; wave0 does dir+mask). Single variable vs R0: each block now
// processes 8 chunks of 64 pairs (a 512-pair row-slice) -> 8 de stores in flight per
// thread instead of 1, testing whether per-wave store-queue depth (not thread count)
// is what separates us (3 TB/s) from fillBufferAligned (6 TB/s on this same buffer).

#define NATOMS 2048
#define NBASIS 20
#define RCUT   5.0f
#define PAIRS_PER_CHUNK 64
#define CHUNKS 8
#define PAIRS_PER_BLOCK (PAIRS_PER_CHUNK * CHUNKS)   // 512
#define BLOCK_THREADS   320   // 64 pairs * 5 quad-slots; de addr = base + c*320 + t

#define DIR_OFF   ((long long)NATOMS * NATOMS * NBASIS)        // floats
#define MASK_OFF  ((long long)NATOMS * NATOMS * (NBASIS + 3))  // floats

__global__ __launch_bounds__(BLOCK_THREADS) void edge_embed_kernel(
    const float* __restrict__ pos, float* __restrict__ out)
{
    const int t = threadIdx.x;
    const int blocksPerRow = NATOMS / PAIRS_PER_BLOCK;          // 4
    const int i  = blockIdx.x / blocksPerRow;                   // wave-uniform
    const int jb = (blockIdx.x % blocksPerRow) * PAIRS_PER_BLOCK;

    const int p = t / 5;            // pair slot 0..63
    const int q = t - 5 * p;        // quad 0..4 (k = 4q+1 .. 4q+4)

    const float xi = pos[3 * i + 0], yi = pos[3 * i + 1], zi = pos[3 * i + 2];

    float4* __restrict__ de = (float4*)out;
    const long long deBase = ((long long)i * NATOMS + jb) * 5;  // quad index of chunk 0

#pragma unroll
    for (int c = 0; c < CHUNKS; ++c) {
        const int j = jb + c * PAIRS_PER_CHUNK + p;
        const float xj = pos[3 * j + 0], yj = pos[3 * j + 1], zj = pos[3 * j + 2];
        const float dx = xi - xj, dy = yi - yj, dz = zi - zj;
        float d2;
        {
            // match numpy's unfused rounding so the dist<r mask can't flip at the boundary
#pragma clang fp contract(off)
            d2 = (dx * dx + dy * dy) + dz * dz;
        }
        const float dist = sqrtf(d2);
        const bool m = (dist < RCUT) && (i != j);

        float4 v = make_float4(0.0f, 0.0f, 0.0f, 0.0f);
        if (m) {   // ~0.8% of lanes
            const float x  = dist * (1.0f / RCUT);
            const float x2 = x * x, x4 = x2 * x2, x8 = x4 * x4, x9 = x8 * x;
            const float env = 1.0f - 55.0f * x9 + 99.0f * x9 * x - 45.0f * x9 * x2;
            const float scale = env / x;
            const float theta = 3.14159265358979323846f * x;
            const float k0 = (float)(4 * q + 1);
            const float s0 = sinf(k0 * theta);
            const float s1 = sinf((k0 + 1.0f) * theta);
            const float twoc = 2.0f * cosf(theta);
            const float s2 = twoc * s1 - s0;
            const float s3 = twoc * s2 - s1;
            v = make_float4(scale * s0, scale * s1, scale * s2, scale * s3);
        }
        // contiguous 16B per lane: quad index = deBase + c*320 + t
        de[deBase + c * (PAIRS_PER_CHUNK * 5) + t] = v;
    }

    if (t < PAIRS_PER_CHUNK) {
        // wave 0: dir (3 dwords, stride 12B) + mask (coalesced), 8 chunks deep
#pragma unroll
        for (int c = 0; c < CHUNKS; ++c) {
            const int j2 = jb + c * PAIRS_PER_CHUNK + t;
            const float xj2 = pos[3 * j2 + 0], yj2 = pos[3 * j2 + 1], zj2 = pos[3 * j2 + 2];
            const float ex = xi - xj2, ey = yi - yj2, ez = zi - zj2;
            float e2;
            {
#pragma clang fp contract(off)
                e2 = (ex * ex + ey * ey) + ez * ez;
            }
            const float ed = sqrtf(e2);
            const bool m2 = (ed < RCUT) && (i != j2);
            float ox = 0.0f, oy = 0.0f, oz = 0.0f, mv = 0.0f;
            if (m2) { ox = ex / ed; oy = ey / ed; oz = ez / ed; mv = 1.0f; }
            const long long pair2 = (long long)i * NATOMS + j2;
            float* __restrict__ dir = out + DIR_OFF + pair2 * 3;
            dir[0] = ox; dir[1] = oy; dir[2] = oz;
            out[MASK_OFF + pair2] = mv;
        }
    }
}

extern "C" void kernel_launch(void* const* d_in, const int* in_sizes, int n_in,
                              void* d_out, int out_size, void* d_ws, size_t ws_size,
                              hipStream_t stream) {
    const float* pos = (const float*)d_in[0];
    float* out = (float*)d_out;
    // 2048 rows * 4 blocks/row, 320 threads (64 pairs x 5 quads) per block, 8 chunks each
    edge_embed_kernel<<<dim3(NATOMS * (NATOMS / PAIRS_PER_BLOCK)), dim3(BLOCK_THREADS), 0, stream>>>(pos, out);
}